// Round 6
// baseline (382.341 us; speedup 1.0000x reference)
//
#include <hip/hip_runtime.h>
#include <hip/hip_bf16.h>
#include <math.h>

#define DHID 128
#define SH 7                 // nodes per bucket = 128
#define BIN_T 2048           // edges per bin_edges block
#define CAPSH 12             // staged capacity per bucket = 4096 (avg fill ~2046)
#define SRC_SH 13            // src-range granularity = 8192 nodes (~2MB bf16 rows); N<=131072

typedef __attribute__((ext_vector_type(8))) short bf16x8;
typedef __attribute__((ext_vector_type(4))) float f32x4;

__device__ __forceinline__ int atomAddI(int* p, int v) {
    return __hip_atomic_fetch_add(p, v, __ATOMIC_RELAXED, __HIP_MEMORY_SCOPE_AGENT);
}
__device__ __forceinline__ float bf_lo(unsigned u) { return __uint_as_float(u << 16); }
__device__ __forceinline__ float bf_hi(unsigned u) { return __uint_as_float(u & 0xffff0000u); }
__device__ __forceinline__ unsigned short bf16_1(float f) {
    unsigned u = __float_as_uint(f);
    u += 0x7fffu + ((u >> 16) & 1u);   // RNE
    return (unsigned short)(u >> 16);
}
__device__ __forceinline__ unsigned pack_bf16x2(float a, float b) {
    unsigned ua = __float_as_uint(a);
    unsigned ub = __float_as_uint(b);
    ua = (ua + 0x7fffu + ((ua >> 16) & 1u)) >> 16;
    ub = (ub + 0x7fffu + ((ub >> 16) & 1u)) & 0xffff0000u;
    return ua | ub;
}

// ---- phase 1: single-pass reg-staged binning; LDS histogram -> chunk reservation -> write ----
// blocks >= nb_bin do weight bf16 prep + per-graph 1/count (independent work folded in).
__global__ __launch_bounds__(256) void bin_edges(const int* __restrict__ src,
                                                 const int* __restrict__ dst,
                                                 int* __restrict__ bcur,
                                                 unsigned* __restrict__ staged,
                                                 const float* __restrict__ W1,
                                                 const float* __restrict__ W2,
                                                 const float* __restrict__ Wih,
                                                 unsigned short* __restrict__ Wt1,
                                                 unsigned short* __restrict__ Wt2,
                                                 unsigned short* __restrict__ Wihb,
                                                 const int* __restrict__ batch,
                                                 float* __restrict__ cnt_inv,
                                                 int E, int NB, int nb_bin, int Nn, int G) {
    int t = threadIdx.x;
    if (blockIdx.x >= nb_bin) {
        int idx = (blockIdx.x - nb_bin) * 256 + t;
        if (idx < 16384) {
            int k = idx >> 7, n = idx & 127;
            Wt1[n * 128 + k] = bf16_1(W1[idx]);
        } else if (idx < 32768) {
            int j = idx - 16384;
            int k = j >> 7, n = j & 127;
            Wt2[n * 128 + k] = bf16_1(W2[j]);
        } else if (idx < 32768 + 49152) {
            int j = idx - 32768;
            Wihb[j] = bf16_1(Wih[j]);
        } else if (idx < 81920 + G) {
            int g = idx - 81920;
            int lo = 0, hi = Nn;
            while (lo < hi) { int mid = (lo + hi) >> 1; if (batch[mid] < g) lo = mid + 1; else hi = mid; }
            int s = lo;
            hi = Nn;
            while (lo < hi) { int mid = (lo + hi) >> 1; if (batch[mid] < g + 1) lo = mid + 1; else hi = mid; }
            cnt_inv[g] = 1.0f / fmaxf((float)(lo - s), 1.0f);
        }
        return;
    }
    __shared__ int lh[1024], lbase[1024], lcur[1024];
    int e0 = blockIdx.x * BIN_T;
    int eend = min(e0 + BIN_T, E);
    for (int i = t; i < NB; i += 256) { lh[i] = 0; lcur[i] = 0; }
    __syncthreads();
    // stage the block's edges in registers (8 per thread): one pass over src/dst
    int sv[8], dv[8];
#pragma unroll
    for (int i = 0; i < 8; i++) {
        int e = e0 + t + i * 256;
        if (e < eend) { sv[i] = src[e]; dv[i] = dst[e]; }
        else { sv[i] = 0; dv[i] = -1; }
    }
#pragma unroll
    for (int i = 0; i < 8; i++)
        if (dv[i] >= 0) atomicAdd(&lh[dv[i] >> SH], 1);
    __syncthreads();
    for (int i = t; i < NB; i += 256)
        lbase[i] = lh[i] ? atomAddI(&bcur[i], lh[i]) : 0;
    __syncthreads();
#pragma unroll
    for (int i = 0; i < 8; i++) {
        if (dv[i] >= 0) {
            int d = dv[i];
            int b = d >> SH;
            int pos = lbase[b] + atomicAdd(&lcur[b], 1);
            staged[((size_t)b << CAPSH) + pos] =
                (unsigned)sv[i] | ((unsigned)(d & ((1 << SH) - 1)) << 24);
        }
    }
}

// ---- phase 2 + gemm1 fused dispatch: blocks [0,NB) sort buckets into CSR; blocks
// [NB, NB+nb_g) run the (independent) X @ W1^T MFMA gemm. ----
__global__ __launch_bounds__(256) void scatter_gemm(const unsigned* __restrict__ staged,
                                                    const int* __restrict__ bcur,
                                                    int* __restrict__ off,
                                                    float* __restrict__ dinv,
                                                    int* __restrict__ rec,
                                                    int N, int E, int NB,
                                                    const float* __restrict__ Xf,
                                                    const unsigned short* __restrict__ Wt,
                                                    unsigned short* __restrict__ Y) {
    __shared__ __align__(16) unsigned char smem[52224];
    const int tid = threadIdx.x;
    if (blockIdx.x < NB) {
        // -------- counting sort by (dst-local, src-range); 128 nodes/bucket --------
        int* hist = (int*)smem;              // 2048 ints
        int* sh   = (int*)(smem + 8192);     // 256 ints
        int t = tid;
        int b = blockIdx.x;
        int node0 = b << SH;

        // base = sum of bcur[0..b-1]  (NB <= 1024)
        int s0 = (t < b) ? bcur[t] : 0;
        int s1 = (256 + t < b) ? bcur[256 + t] : 0;
        int s2 = (512 + t < b) ? bcur[512 + t] : 0;
        int s3 = (768 + t < b) ? bcur[768 + t] : 0;
        int s = s0 + s1 + s2 + s3;
#pragma unroll
        for (int o = 1; o < 64; o <<= 1) s += __shfl_xor(s, o);
        if ((t & 63) == 0) sh[t >> 6] = s;
        __syncthreads();
        int base = sh[0] + sh[1] + sh[2] + sh[3];
        __syncthreads();

        // histogram over 2048 keys: key = (dl<<4) | src_range
        for (int i = t; i < 2048; i += 256) hist[i] = 0;
        __syncthreads();
        int cnt_b = bcur[b];
        const unsigned* st = staged + ((size_t)b << CAPSH);
        for (int j = t; j < cnt_b; j += 256) {
            unsigned w = st[j];
            int key = (int)((w >> 24) << 4) | (int)((w & 0xFFFFFFu) >> SRC_SH);
            atomicAdd(&hist[key], 1);
        }
        __syncthreads();

        // hierarchical exclusive scan: thread t<128 owns node t's 16 range-counters
        int loc[16];
        int run = 0;
        if (t < 128) {
            int base16 = t * 16;
#pragma unroll
            for (int i = 0; i < 16; i++) { loc[i] = run; run += hist[base16 + i]; }
        }
        sh[t] = (t < 128) ? run : 0;
        __syncthreads();
#pragma unroll
        for (int o = 1; o < 256; o <<= 1) {
            int x = (t >= o) ? sh[t - o] : 0;
            __syncthreads();
            sh[t] += x;
            __syncthreads();
        }
        int excl = sh[t] - run;          // node t's offset within bucket (t<128)
        if (t < 128) {
            int base16 = t * 16;
#pragma unroll
            for (int i = 0; i < 16; i++) hist[base16 + i] = base + excl + loc[i];
            int node = node0 + t;
            if (node < N) {
                off[node] = base + excl;
                dinv[node] = rsqrtf((float)run + 1.0f);
            }
        }
        if (b == NB - 1 && t == 0) off[N] = E;
        __syncthreads();

        // scatter in sorted order via per-key cursors
        for (int j = t; j < cnt_b; j += 256) {
            unsigned w = st[j];
            int key = (int)((w >> 24) << 4) | (int)((w & 0xFFFFFFu) >> SRC_SH);
            int pos = atomicAdd(&hist[key], 1);
            rec[pos] = (int)(w & 0xFFFFFFu);
        }
    } else {
        // -------- gemm1: Y_bf16[64,128] = Xf[64,128] @ Wt^T --------
        unsigned short* Xs = (unsigned short*)smem;            // 64*136
        unsigned short* Ws = (unsigned short*)(smem + 17408);  // 128*136
        {
            const uint4* W4 = (const uint4*)Wt;
#pragma unroll
            for (int i = 0; i < 8; i++) {
                int idx = tid + i * 256;
                int r = idx >> 4, c8 = idx & 15;
                *(uint4*)&Ws[r * 136 + c8 * 8] = W4[idx];
            }
        }
        const int row0 = (blockIdx.x - NB) * 64;
        {
            const float4* X4 = (const float4*)Xf;
#pragma unroll
            for (int i = 0; i < 8; i++) {
                int idx = tid + i * 256;
                int r = idx >> 5, c4 = idx & 31;
                float4 v = make_float4(0.f, 0.f, 0.f, 0.f);
                if (row0 + r < N) v = X4[(size_t)(row0 + r) * 32 + c4];
                uint2 pk = make_uint2(pack_bf16x2(v.x, v.y), pack_bf16x2(v.z, v.w));
                *(uint2*)&Xs[r * 136 + c4 * 4] = pk;
            }
        }
        __syncthreads();

        const int lane = tid & 63;
        const int wv = tid >> 6;
        const int m = lane & 15, quad = lane >> 4;
        const int wrow = wv * 16;

        f32x4 acc[8];
#pragma unroll
        for (int i = 0; i < 8; i++) acc[i] = (f32x4){0.f, 0.f, 0.f, 0.f};

#pragma unroll
        for (int kc = 0; kc < 4; kc++) {
            bf16x8 a = *(const bf16x8*)&Xs[(wrow + m) * 136 + kc * 32 + quad * 8];
#pragma unroll
            for (int nt = 0; nt < 8; nt++) {
                bf16x8 bfr = *(const bf16x8*)&Ws[(nt * 16 + m) * 136 + kc * 32 + quad * 8];
                acc[nt] = __builtin_amdgcn_mfma_f32_16x16x32_bf16(a, bfr, acc[nt], 0, 0, 0);
            }
        }

#pragma unroll
        for (int r = 0; r < 4; r++) {
            int lrow = wrow + quad * 4 + r;
#pragma unroll
            for (int nt = 0; nt < 8; nt++)
                Xs[lrow * 136 + nt * 16 + m] = bf16_1(acc[nt][r]);
        }
        __syncthreads();
#pragma unroll
        for (int i = 0; i < 4; i++) {
            int idx = tid + i * 256;
            int r = idx >> 4, c8 = idx & 15;
            if (row0 + r < N)
                *(uint4*)&Y[(size_t)(row0 + r) * DHID + c8 * 8] =
                    *(const uint4*)&Xs[r * 136 + c8 * 8];
        }
    }
}

// ---------------- CSR aggregate (layer 1): quarter-wave uint4 gathers, bf16 out ----------------
// float2 accumulators (packed f32 math) + software-pipelined rec loads. (2-deep; the
// proven 64-µs plateau form.)
__global__ __launch_bounds__(256) void aggregate(const unsigned short* __restrict__ A,
                                                 const float* __restrict__ dinv,
                                                 const int* __restrict__ off,
                                                 const int* __restrict__ rec,
                                                 const float* __restrict__ bias,
                                                 unsigned short* __restrict__ Bout,
                                                 int N, int mode) {
    int node = blockIdx.x * 4 + (threadIdx.x >> 6);
    if (node >= N) return;
    int lane = threadIdx.x & 63;
    int q  = lane >> 4;
    int ql = lane & 15;
    float di = dinv[node];
    float2 acc[4];
    if (q == 0) {
        float s = di * di;
        uint4 v = ((const uint4*)(A + (size_t)node * DHID))[ql];
        const float4* bb = (const float4*)(bias + ql * 8);
        float4 b0 = bb[0], b1 = bb[1];
        acc[0] = make_float2(bf_lo(v.x) * s + b0.x, bf_hi(v.x) * s + b0.y);
        acc[1] = make_float2(bf_lo(v.y) * s + b0.z, bf_hi(v.y) * s + b0.w);
        acc[2] = make_float2(bf_lo(v.z) * s + b1.x, bf_hi(v.z) * s + b1.y);
        acc[3] = make_float2(bf_lo(v.w) * s + b1.z, bf_hi(v.w) * s + b1.w);
    } else {
#pragma unroll
        for (int i = 0; i < 4; i++) acc[i] = make_float2(0.f, 0.f);
    }
    int j = off[node] + q;
    int jend = off[node + 1];
    if (j + 4 < jend) {
        int s0 = rec[j], s1 = rec[j + 4];
        for (; j + 12 < jend; j += 8) {
            int n0 = rec[j + 8], n1 = rec[j + 12];      // prefetch next pair
            uint4 v0 = ((const uint4*)(A + (size_t)s0 * DHID))[ql];
            uint4 v1 = ((const uint4*)(A + (size_t)s1 * DHID))[ql];
            float w0 = dinv[s0] * di;
            float w1 = dinv[s1] * di;
            acc[0].x += bf_lo(v0.x) * w0 + bf_lo(v1.x) * w1;
            acc[0].y += bf_hi(v0.x) * w0 + bf_hi(v1.x) * w1;
            acc[1].x += bf_lo(v0.y) * w0 + bf_lo(v1.y) * w1;
            acc[1].y += bf_hi(v0.y) * w0 + bf_hi(v1.y) * w1;
            acc[2].x += bf_lo(v0.z) * w0 + bf_lo(v1.z) * w1;
            acc[2].y += bf_hi(v0.z) * w0 + bf_hi(v1.z) * w1;
            acc[3].x += bf_lo(v0.w) * w0 + bf_lo(v1.w) * w1;
            acc[3].y += bf_hi(v0.w) * w0 + bf_hi(v1.w) * w1;
            s0 = n0; s1 = n1;
        }
        {
            uint4 v0 = ((const uint4*)(A + (size_t)s0 * DHID))[ql];
            uint4 v1 = ((const uint4*)(A + (size_t)s1 * DHID))[ql];
            float w0 = dinv[s0] * di;
            float w1 = dinv[s1] * di;
            acc[0].x += bf_lo(v0.x) * w0 + bf_lo(v1.x) * w1;
            acc[0].y += bf_hi(v0.x) * w0 + bf_hi(v1.x) * w1;
            acc[1].x += bf_lo(v0.y) * w0 + bf_lo(v1.y) * w1;
            acc[1].y += bf_hi(v0.y) * w0 + bf_hi(v1.y) * w1;
            acc[2].x += bf_lo(v0.z) * w0 + bf_lo(v1.z) * w1;
            acc[2].y += bf_hi(v0.z) * w0 + bf_hi(v1.z) * w1;
            acc[3].x += bf_lo(v0.w) * w0 + bf_lo(v1.w) * w1;
            acc[3].y += bf_hi(v0.w) * w0 + bf_hi(v1.w) * w1;
            j += 8;
        }
    }
    if (j < jend) {
        int s0 = rec[j];
        uint4 v0 = ((const uint4*)(A + (size_t)s0 * DHID))[ql];
        float w0 = dinv[s0] * di;
        acc[0].x += bf_lo(v0.x) * w0;
        acc[0].y += bf_hi(v0.x) * w0;
        acc[1].x += bf_lo(v0.y) * w0;
        acc[1].y += bf_hi(v0.y) * w0;
        acc[2].x += bf_lo(v0.z) * w0;
        acc[2].y += bf_hi(v0.z) * w0;
        acc[3].x += bf_lo(v0.w) * w0;
        acc[3].y += bf_hi(v0.w) * w0;
    }
#pragma unroll
    for (int i = 0; i < 4; i++) {
        acc[i].x += __shfl_xor(acc[i].x, 16);
        acc[i].y += __shfl_xor(acc[i].y, 16);
        acc[i].x += __shfl_xor(acc[i].x, 32);
        acc[i].y += __shfl_xor(acc[i].y, 32);
    }
    if (q == 0) {
        if (mode == 1) {
#pragma unroll
            for (int i = 0; i < 4; i++) {
                acc[i].x = fmaxf(acc[i].x, 0.f);
                acc[i].y = fmaxf(acc[i].y, 0.f);
            }
        }
        uint4 pk;
        pk.x = pack_bf16x2(acc[0].x, acc[0].y);
        pk.y = pack_bf16x2(acc[1].x, acc[1].y);
        pk.z = pack_bf16x2(acc[2].x, acc[2].y);
        pk.w = pack_bf16x2(acc[3].x, acc[3].y);
        ((uint4*)(Bout + (size_t)node * DHID))[ql] = pk;
    }
}

// ---------------- CSR aggregate (layer 2) fused with mean-pool ----------------
// Same gather; no bias (b2 applied in tail, valid since pool/agg commute with +b2).
// After the butterfly reduce ALL lanes hold the row, so the 128 atomics per node are
// spread 2-per-lane across the wave. Output accumulates the per-graph MEAN directly
// (prescaled by cnt_inv) into the 1MB f32 gbuf (L2-resident atomics).
__global__ __launch_bounds__(256) void aggregate_pool(const unsigned short* __restrict__ A,
                                                      const float* __restrict__ dinv,
                                                      const int* __restrict__ off,
                                                      const int* __restrict__ rec,
                                                      const int* __restrict__ batch,
                                                      const float* __restrict__ cnt_inv,
                                                      float* __restrict__ gbuf,
                                                      int N) {
    int node = blockIdx.x * 4 + (threadIdx.x >> 6);
    if (node >= N) return;
    int lane = threadIdx.x & 63;
    int q  = lane >> 4;
    int ql = lane & 15;
    float di = dinv[node];
    float2 acc[4];
    if (q == 0) {
        float s = di * di;
        uint4 v = ((const uint4*)(A + (size_t)node * DHID))[ql];
        acc[0] = make_float2(bf_lo(v.x) * s, bf_hi(v.x) * s);
        acc[1] = make_float2(bf_lo(v.y) * s, bf_hi(v.y) * s);
        acc[2] = make_float2(bf_lo(v.z) * s, bf_hi(v.z) * s);
        acc[3] = make_float2(bf_lo(v.w) * s, bf_hi(v.w) * s);
    } else {
#pragma unroll
        for (int i = 0; i < 4; i++) acc[i] = make_float2(0.f, 0.f);
    }
    int j = off[node] + q;
    int jend = off[node + 1];
    if (j + 4 < jend) {
        int s0 = rec[j], s1 = rec[j + 4];
        for (; j + 12 < jend; j += 8) {
            int n0 = rec[j + 8], n1 = rec[j + 12];      // prefetch next pair
            uint4 v0 = ((const uint4*)(A + (size_t)s0 * DHID))[ql];
            uint4 v1 = ((const uint4*)(A + (size_t)s1 * DHID))[ql];
            float w0 = dinv[s0] * di;
            float w1 = dinv[s1] * di;
            acc[0].x += bf_lo(v0.x) * w0 + bf_lo(v1.x) * w1;
            acc[0].y += bf_hi(v0.x) * w0 + bf_hi(v1.x) * w1;
            acc[1].x += bf_lo(v0.y) * w0 + bf_lo(v1.y) * w1;
            acc[1].y += bf_hi(v0.y) * w0 + bf_hi(v1.y) * w1;
            acc[2].x += bf_lo(v0.z) * w0 + bf_lo(v1.z) * w1;
            acc[2].y += bf_hi(v0.z) * w0 + bf_hi(v1.z) * w1;
            acc[3].x += bf_lo(v0.w) * w0 + bf_lo(v1.w) * w1;
            acc[3].y += bf_hi(v0.w) * w0 + bf_hi(v1.w) * w1;
            s0 = n0; s1 = n1;
        }
        {
            uint4 v0 = ((const uint4*)(A + (size_t)s0 * DHID))[ql];
            uint4 v1 = ((const uint4*)(A + (size_t)s1 * DHID))[ql];
            float w0 = dinv[s0] * di;
            float w1 = dinv[s1] * di;
            acc[0].x += bf_lo(v0.x) * w0 + bf_lo(v1.x) * w1;
            acc[0].y += bf_hi(v0.x) * w0 + bf_hi(v1.x) * w1;
            acc[1].x += bf_lo(v0.y) * w0 + bf_lo(v1.y) * w1;
            acc[1].y += bf_hi(v0.y) * w0 + bf_hi(v1.y) * w1;
            acc[2].x += bf_lo(v0.z) * w0 + bf_lo(v1.z) * w1;
            acc[2].y += bf_hi(v0.z) * w0 + bf_hi(v1.z) * w1;
            acc[3].x += bf_lo(v0.w) * w0 + bf_lo(v1.w) * w1;
            acc[3].y += bf_hi(v0.w) * w0 + bf_hi(v1.w) * w1;
            j += 8;
        }
    }
    if (j < jend) {
        int s0 = rec[j];
        uint4 v0 = ((const uint4*)(A + (size_t)s0 * DHID))[ql];
        float w0 = dinv[s0] * di;
        acc[0].x += bf_lo(v0.x) * w0;
        acc[0].y += bf_hi(v0.x) * w0;
        acc[1].x += bf_lo(v0.y) * w0;
        acc[1].y += bf_hi(v0.y) * w0;
        acc[2].x += bf_lo(v0.z) * w0;
        acc[2].y += bf_hi(v0.z) * w0;
        acc[3].x += bf_lo(v0.w) * w0;
        acc[3].y += bf_hi(v0.w) * w0;
    }
#pragma unroll
    for (int i = 0; i < 4; i++) {
        acc[i].x += __shfl_xor(acc[i].x, 16);
        acc[i].y += __shfl_xor(acc[i].y, 16);
        acc[i].x += __shfl_xor(acc[i].x, 32);
        acc[i].y += __shfl_xor(acc[i].y, 32);
    }
    // every lane now holds the full reduced row for its ql's 8 channels;
    // quarter q contributes channels ql*8 + 2q, ql*8 + 2q + 1.
    int g = batch[node];
    float sc = cnt_inv[g];
    float* dstp = gbuf + (size_t)g * DHID + ql * 8 + 2 * q;
    atomicAdd(dstp,     acc[q].x * sc);
    atomicAdd(dstp + 1, acc[q].y * sc);
}

// ---------------- fused tail: (pooled mean) @ W2 + b2 -> GRU gates -> LN -> head ----------------
// One block per graph; gbuf already holds mean(Â·H1). Layer-2's W2 (commuted past agg+pool)
// is applied here: g2 = grow @ W2 + b2 (128 dots of length 128 vs 100k-row gemm).
__global__ __launch_bounds__(256) void tail_head(const float* __restrict__ gbuf,
                                                 const unsigned short* __restrict__ Wt2,
                                                 const float* __restrict__ b2,
                                                 const unsigned short* __restrict__ Wihb,
                                                 const float* __restrict__ b_ih,
                                                 const float* __restrict__ b_hh,
                                                 const float* __restrict__ W_lin,
                                                 const float* __restrict__ b_lin,
                                                 float* __restrict__ out, int G) {
    __shared__ float grow[128];
    __shared__ float g2[128];
    __shared__ float gi[384];
    __shared__ float red[4];
    const int t = threadIdx.x;
    const int g = blockIdx.x;

    if (t < 128) grow[t] = gbuf[(size_t)g * DHID + t];
    __syncthreads();

    // g2[n] = dot(grow, W2[:,n]) + b2[n]   (Wt2 row n = column n of W2, bf16)
    if (t < 128) {
        float a = 0.f;
        const uint4* wr = (const uint4*)(Wt2 + (size_t)t * DHID);
#pragma unroll
        for (int k8 = 0; k8 < 16; k8++) {
            uint4 wv = wr[k8];
            const float* gk = &grow[k8 * 8];
            a += bf_lo(wv.x) * gk[0] + bf_hi(wv.x) * gk[1]
               + bf_lo(wv.y) * gk[2] + bf_hi(wv.y) * gk[3]
               + bf_lo(wv.z) * gk[4] + bf_hi(wv.z) * gk[5]
               + bf_lo(wv.w) * gk[6] + bf_hi(wv.w) * gk[7];
        }
        g2[t] = a + b2[t];
    }
    __syncthreads();

    // gi[o] = dot(g2, Wih[o,:]); thread t handles o=t, and o=256+t for t<128
    {
        float a0 = 0.f;
        const uint4* wr = (const uint4*)(Wihb + (size_t)t * DHID);
#pragma unroll
        for (int k8 = 0; k8 < 16; k8++) {
            uint4 wv = wr[k8];
            const float* gk = &g2[k8 * 8];
            a0 += bf_lo(wv.x) * gk[0] + bf_hi(wv.x) * gk[1]
                + bf_lo(wv.y) * gk[2] + bf_hi(wv.y) * gk[3]
                + bf_lo(wv.z) * gk[4] + bf_hi(wv.z) * gk[5]
                + bf_lo(wv.w) * gk[6] + bf_hi(wv.w) * gk[7];
        }
        gi[t] = a0;
    }
    if (t < 128) {
        float a1 = 0.f;
        const uint4* wr = (const uint4*)(Wihb + (size_t)(256 + t) * DHID);
#pragma unroll
        for (int k8 = 0; k8 < 16; k8++) {
            uint4 wv = wr[k8];
            const float* gk = &g2[k8 * 8];
            a1 += bf_lo(wv.x) * gk[0] + bf_hi(wv.x) * gk[1]
                + bf_lo(wv.y) * gk[2] + bf_hi(wv.y) * gk[3]
                + bf_lo(wv.z) * gk[4] + bf_hi(wv.z) * gk[5]
                + bf_lo(wv.w) * gk[6] + bf_hi(wv.w) * gk[7];
        }
        gi[256 + t] = a1;
    }
    __syncthreads();

    float y = 0.f, wl = 0.f;
    if (t < 128) {
        float d0 = gi[t], d1 = gi[128 + t], d2 = gi[256 + t];
        float rg = 1.f / (1.f + expf(-(d0 + b_ih[t] + b_hh[t])));
        float zg = 1.f / (1.f + expf(-(d1 + b_ih[128 + t] + b_hh[128 + t])));
        float ng = tanhf(d2 + b_ih[256 + t] + rg * b_hh[256 + t]);
        y = fmaxf((1.f - zg) * ng, 0.f);
        wl = W_lin[t];
    }
    auto blockSum = [&](float v) -> float {
#pragma unroll
        for (int o = 1; o < 64; o <<= 1) v += __shfl_xor(v, o);
        __syncthreads();
        if ((t & 63) == 0) red[t >> 6] = v;
        __syncthreads();
        return red[0] + red[1] + red[2] + red[3];
    };
    float mu = blockSum(y) * (1.f / 128.f);
    float dy = (t < 128) ? (y - mu) : 0.f;
    float var = blockSum(dy * dy) * (1.f / 128.f);
    float yn = dy * rsqrtf(var + 1e-5f);
    float tot = blockSum(yn * wl);
    if (t == 0) out[g] = tot + b_lin[0];
}

extern "C" void kernel_launch(void* const* d_in, const int* in_sizes, int n_in,
                              void* d_out, int out_size, void* d_ws, size_t ws_size,
                              hipStream_t stream) {
    const float* x     = (const float*)d_in[0];
    const int*   ei    = (const int*)d_in[1];
    const int*   batch = (const int*)d_in[2];
    const float* W1    = (const float*)d_in[3];
    const float* b1    = (const float*)d_in[4];
    const float* W2    = (const float*)d_in[5];
    const float* b2    = (const float*)d_in[6];
    const float* W_ih  = (const float*)d_in[7];
    // d_in[8] = W_hh unused (h0 == 0)
    const float* b_ih  = (const float*)d_in[9];
    const float* b_hh  = (const float*)d_in[10];
    const float* W_lin = (const float*)d_in[11];
    const float* b_lin = (const float*)d_in[12];
    float* out = (float*)d_out;

    const int N = in_sizes[0] / DHID;
    const int E = in_sizes[1] / 2;
    const int G = out_size;
    const int* src = ei;
    const int* dst = ei + E;
    const int NB = (N + (1 << SH) - 1) >> SH;   // buckets (<= 1024)

    auto align256 = [](size_t v) { return (v + 255) & ~(size_t)255; };
    char* p = (char*)d_ws;
    size_t used = 0;
    auto carve = [&](size_t bytes) -> char* {
        char* q = p + used;
        used += align256(bytes);
        return q;
    };

    int*   off    = (int*)carve(((size_t)N + 1) * 4);
    int*   bcur   = (int*)carve(1024 * 4);                     // contiguous with gbuf:
    float* gbuf   = (float*)carve((size_t)G * DHID * 4);       // one memset covers both
    float* dinv   = (float*)carve((size_t)N * 4);
    float* cnt_inv = (float*)carve((size_t)G * 4);
    unsigned* staged = (unsigned*)carve(((size_t)NB << CAPSH) * 4);
    int*   rec    = (int*)carve((size_t)E * 4);
    unsigned short* Wt1  = (unsigned short*)carve((size_t)128 * 128 * 2);
    unsigned short* Wt2  = (unsigned short*)carve((size_t)128 * 128 * 2);
    unsigned short* Wihb = (unsigned short*)carve((size_t)3 * 128 * 128 * 2);
    unsigned short* A    = (unsigned short*)carve((size_t)N * DHID * 2);   // bf16: x@W1
    unsigned short* B1b  = (unsigned short*)carve((size_t)N * DHID * 2);   // bf16: H1 (relu'd)

    dim3 blk(256);
    int nb_g  = (N + 63) / 64;
    int nb_ag = (N + 3) / 4;
    int nb_bin = (E + BIN_T - 1) / BIN_T;
    int nb_wp  = (81920 + G + 255) / 256;

    // ---- CSR build (weight prep + per-graph counts folded into bin_edges) ----
    hipMemsetAsync(bcur, 0, 1024 * 4 + (size_t)G * DHID * 4, stream);
    bin_edges<<<nb_bin + nb_wp, blk, 0, stream>>>(src, dst, bcur, staged,
                                                  W1, W2, W_ih, Wt1, Wt2, Wihb,
                                                  batch, cnt_inv,
                                                  E, NB, nb_bin, N, G);
    scatter_gemm<<<NB + nb_g, blk, 0, stream>>>(staged, bcur, off, dinv, rec,
                                                N, E, NB, x, Wt1, A);

    // ---- layer 1: B1b = ReLU(Â·A + b1) ----
    aggregate<<<nb_ag, blk, 0, stream>>>(A, dinv, off, rec, b1, B1b, N, 1);

    // ---- layer 2 aggregation fused with mean-pool (W2, b2 commuted into tail) ----
    aggregate_pool<<<nb_ag, blk, 0, stream>>>(B1b, dinv, off, rec, batch, cnt_inv,
                                              gbuf, N);

    // ---- tail: @W2+b2 -> GRU -> LN -> head ----
    tail_head<<<G, blk, 0, stream>>>(gbuf, Wt2, b2, Wihb, b_ih, b_hh, W_lin, b_lin,
                                     out, G);
}

// Round 7
// 331.721 us; speedup vs baseline: 1.1526x; 1.1526x over previous
//
#include <hip/hip_runtime.h>
#include <hip/hip_bf16.h>
#include <math.h>

#define DHID 128
#define SH 7                 // nodes per bucket = 128
#define BIN_T 2048           // edges per bin_edges block
#define CAPSH 12             // staged capacity per bucket = 4096 (avg fill ~2046)
#define SRC_SH 13            // src-range granularity = 8192 nodes (~2MB bf16 rows); N<=131072

typedef __attribute__((ext_vector_type(8))) short bf16x8;
typedef __attribute__((ext_vector_type(4))) float f32x4;

__device__ __forceinline__ int atomAddI(int* p, int v) {
    return __hip_atomic_fetch_add(p, v, __ATOMIC_RELAXED, __HIP_MEMORY_SCOPE_AGENT);
}
__device__ __forceinline__ float bf_lo(unsigned u) { return __uint_as_float(u << 16); }
__device__ __forceinline__ float bf_hi(unsigned u) { return __uint_as_float(u & 0xffff0000u); }
__device__ __forceinline__ unsigned short bf16_1(float f) {
    unsigned u = __float_as_uint(f);
    u += 0x7fffu + ((u >> 16) & 1u);   // RNE
    return (unsigned short)(u >> 16);
}
__device__ __forceinline__ unsigned pack_bf16x2(float a, float b) {
    unsigned ua = __float_as_uint(a);
    unsigned ub = __float_as_uint(b);
    ua = (ua + 0x7fffu + ((ua >> 16) & 1u)) >> 16;
    ub = (ub + 0x7fffu + ((ub >> 16) & 1u)) & 0xffff0000u;
    return ua | ub;
}

// ---- phase 1: single-pass reg-staged binning; LDS histogram -> chunk reservation -> write ----
// blocks >= nb_bin do the weight bf16 prep (independent work folded in).
__global__ __launch_bounds__(256) void bin_edges(const int* __restrict__ src,
                                                 const int* __restrict__ dst,
                                                 int* __restrict__ bcur,
                                                 unsigned* __restrict__ staged,
                                                 const float* __restrict__ W1,
                                                 const float* __restrict__ W2,
                                                 const float* __restrict__ Wih,
                                                 unsigned short* __restrict__ Wt1,
                                                 unsigned short* __restrict__ Wt2,
                                                 unsigned short* __restrict__ Wihb,
                                                 int E, int NB, int nb_bin) {
    int t = threadIdx.x;
    if (blockIdx.x >= nb_bin) {
        int idx = (blockIdx.x - nb_bin) * 256 + t;
        if (idx < 16384) {
            int k = idx >> 7, n = idx & 127;
            Wt1[n * 128 + k] = bf16_1(W1[idx]);
        } else if (idx < 32768) {
            int j = idx - 16384;
            int k = j >> 7, n = j & 127;
            Wt2[n * 128 + k] = bf16_1(W2[j]);
        } else if (idx < 32768 + 49152) {
            int j = idx - 32768;
            Wihb[j] = bf16_1(Wih[j]);
        }
        return;
    }
    __shared__ int lh[1024], lbase[1024], lcur[1024];
    int e0 = blockIdx.x * BIN_T;
    int eend = min(e0 + BIN_T, E);
    for (int i = t; i < NB; i += 256) { lh[i] = 0; lcur[i] = 0; }
    __syncthreads();
    // stage the block's edges in registers (8 per thread): one pass over src/dst
    int sv[8], dv[8];
#pragma unroll
    for (int i = 0; i < 8; i++) {
        int e = e0 + t + i * 256;
        if (e < eend) { sv[i] = src[e]; dv[i] = dst[e]; }
        else { sv[i] = 0; dv[i] = -1; }
    }
#pragma unroll
    for (int i = 0; i < 8; i++)
        if (dv[i] >= 0) atomicAdd(&lh[dv[i] >> SH], 1);
    __syncthreads();
    for (int i = t; i < NB; i += 256)
        lbase[i] = lh[i] ? atomAddI(&bcur[i], lh[i]) : 0;
    __syncthreads();
#pragma unroll
    for (int i = 0; i < 8; i++) {
        if (dv[i] >= 0) {
            int d = dv[i];
            int b = d >> SH;
            int pos = lbase[b] + atomicAdd(&lcur[b], 1);
            staged[((size_t)b << CAPSH) + pos] =
                (unsigned)sv[i] | ((unsigned)(d & ((1 << SH) - 1)) << 24);
        }
    }
}

// ---- phase 2 + gemm1 fused dispatch: blocks [0,NB) sort buckets into CSR; blocks
// [NB, NB+nb_g) run the (independent) X @ W1^T MFMA gemm. ----
__global__ __launch_bounds__(256) void scatter_gemm(const unsigned* __restrict__ staged,
                                                    const int* __restrict__ bcur,
                                                    int* __restrict__ off,
                                                    float* __restrict__ dinv,
                                                    int* __restrict__ rec,
                                                    int N, int E, int NB,
                                                    const float* __restrict__ Xf,
                                                    const unsigned short* __restrict__ Wt,
                                                    unsigned short* __restrict__ Y) {
    __shared__ __align__(16) unsigned char smem[52224];
    const int tid = threadIdx.x;
    if (blockIdx.x < NB) {
        // -------- counting sort by (dst-local, src-range); 128 nodes/bucket --------
        int* hist = (int*)smem;              // 2048 ints
        int* sh   = (int*)(smem + 8192);     // 256 ints
        int t = tid;
        int b = blockIdx.x;
        int node0 = b << SH;

        // base = sum of bcur[0..b-1]  (NB <= 1024)
        int s0 = (t < b) ? bcur[t] : 0;
        int s1 = (256 + t < b) ? bcur[256 + t] : 0;
        int s2 = (512 + t < b) ? bcur[512 + t] : 0;
        int s3 = (768 + t < b) ? bcur[768 + t] : 0;
        int s = s0 + s1 + s2 + s3;
#pragma unroll
        for (int o = 1; o < 64; o <<= 1) s += __shfl_xor(s, o);
        if ((t & 63) == 0) sh[t >> 6] = s;
        __syncthreads();
        int base = sh[0] + sh[1] + sh[2] + sh[3];
        __syncthreads();

        // histogram over 2048 keys: key = (dl<<4) | src_range
        for (int i = t; i < 2048; i += 256) hist[i] = 0;
        __syncthreads();
        int cnt_b = bcur[b];
        const unsigned* st = staged + ((size_t)b << CAPSH);
        for (int j = t; j < cnt_b; j += 256) {
            unsigned w = st[j];
            int key = (int)((w >> 24) << 4) | (int)((w & 0xFFFFFFu) >> SRC_SH);
            atomicAdd(&hist[key], 1);
        }
        __syncthreads();

        // hierarchical exclusive scan: thread t<128 owns node t's 16 range-counters
        int loc[16];
        int run = 0;
        if (t < 128) {
            int base16 = t * 16;
#pragma unroll
            for (int i = 0; i < 16; i++) { loc[i] = run; run += hist[base16 + i]; }
        }
        sh[t] = (t < 128) ? run : 0;
        __syncthreads();
#pragma unroll
        for (int o = 1; o < 256; o <<= 1) {
            int x = (t >= o) ? sh[t - o] : 0;
            __syncthreads();
            sh[t] += x;
            __syncthreads();
        }
        int excl = sh[t] - run;          // node t's offset within bucket (t<128)
        if (t < 128) {
            int base16 = t * 16;
#pragma unroll
            for (int i = 0; i < 16; i++) hist[base16 + i] = base + excl + loc[i];
            int node = node0 + t;
            if (node < N) {
                off[node] = base + excl;
                dinv[node] = rsqrtf((float)run + 1.0f);
            }
        }
        if (b == NB - 1 && t == 0) off[N] = E;
        __syncthreads();

        // scatter in sorted order via per-key cursors
        for (int j = t; j < cnt_b; j += 256) {
            unsigned w = st[j];
            int key = (int)((w >> 24) << 4) | (int)((w & 0xFFFFFFu) >> SRC_SH);
            int pos = atomicAdd(&hist[key], 1);
            rec[pos] = (int)(w & 0xFFFFFFu);
        }
    } else {
        // -------- gemm1: Y_bf16[64,128] = Xf[64,128] @ Wt^T --------
        unsigned short* Xs = (unsigned short*)smem;            // 64*136
        unsigned short* Ws = (unsigned short*)(smem + 17408);  // 128*136
        {
            const uint4* W4 = (const uint4*)Wt;
#pragma unroll
            for (int i = 0; i < 8; i++) {
                int idx = tid + i * 256;
                int r = idx >> 4, c8 = idx & 15;
                *(uint4*)&Ws[r * 136 + c8 * 8] = W4[idx];
            }
        }
        const int row0 = (blockIdx.x - NB) * 64;
        {
            const float4* X4 = (const float4*)Xf;
#pragma unroll
            for (int i = 0; i < 8; i++) {
                int idx = tid + i * 256;
                int r = idx >> 5, c4 = idx & 31;
                float4 v = make_float4(0.f, 0.f, 0.f, 0.f);
                if (row0 + r < N) v = X4[(size_t)(row0 + r) * 32 + c4];
                uint2 pk = make_uint2(pack_bf16x2(v.x, v.y), pack_bf16x2(v.z, v.w));
                *(uint2*)&Xs[r * 136 + c4 * 4] = pk;
            }
        }
        __syncthreads();

        const int lane = tid & 63;
        const int wv = tid >> 6;
        const int m = lane & 15, quad = lane >> 4;
        const int wrow = wv * 16;

        f32x4 acc[8];
#pragma unroll
        for (int i = 0; i < 8; i++) acc[i] = (f32x4){0.f, 0.f, 0.f, 0.f};

#pragma unroll
        for (int kc = 0; kc < 4; kc++) {
            bf16x8 a = *(const bf16x8*)&Xs[(wrow + m) * 136 + kc * 32 + quad * 8];
#pragma unroll
            for (int nt = 0; nt < 8; nt++) {
                bf16x8 bfr = *(const bf16x8*)&Ws[(nt * 16 + m) * 136 + kc * 32 + quad * 8];
                acc[nt] = __builtin_amdgcn_mfma_f32_16x16x32_bf16(a, bfr, acc[nt], 0, 0, 0);
            }
        }

#pragma unroll
        for (int r = 0; r < 4; r++) {
            int lrow = wrow + quad * 4 + r;
#pragma unroll
            for (int nt = 0; nt < 8; nt++)
                Xs[lrow * 136 + nt * 16 + m] = bf16_1(acc[nt][r]);
        }
        __syncthreads();
#pragma unroll
        for (int i = 0; i < 4; i++) {
            int idx = tid + i * 256;
            int r = idx >> 4, c8 = idx & 15;
            if (row0 + r < N)
                *(uint4*)&Y[(size_t)(row0 + r) * DHID + c8 * 8] =
                    *(const uint4*)&Xs[r * 136 + c8 * 8];
        }
    }
}

// ---------------- CSR aggregate: quarter-wave uint4 gathers, bf16 out ----------------
// float2 accumulators (packed f32 math) + software-pipelined rec loads. (2-deep; the
// proven 64-µs plateau form.) mode 1 = +bias, relu; mode 0 = +bias only (pass zeros
// for the commuted layer-2 form).
__global__ __launch_bounds__(256) void aggregate(const unsigned short* __restrict__ A,
                                                 const float* __restrict__ dinv,
                                                 const int* __restrict__ off,
                                                 const int* __restrict__ rec,
                                                 const float* __restrict__ bias,
                                                 unsigned short* __restrict__ Bout,
                                                 int N, int mode) {
    int node = blockIdx.x * 4 + (threadIdx.x >> 6);
    if (node >= N) return;
    int lane = threadIdx.x & 63;
    int q  = lane >> 4;
    int ql = lane & 15;
    float di = dinv[node];
    float2 acc[4];
    if (q == 0) {
        float s = di * di;
        uint4 v = ((const uint4*)(A + (size_t)node * DHID))[ql];
        const float4* bb = (const float4*)(bias + ql * 8);
        float4 b0 = bb[0], b1 = bb[1];
        acc[0] = make_float2(bf_lo(v.x) * s + b0.x, bf_hi(v.x) * s + b0.y);
        acc[1] = make_float2(bf_lo(v.y) * s + b0.z, bf_hi(v.y) * s + b0.w);
        acc[2] = make_float2(bf_lo(v.z) * s + b1.x, bf_hi(v.z) * s + b1.y);
        acc[3] = make_float2(bf_lo(v.w) * s + b1.z, bf_hi(v.w) * s + b1.w);
    } else {
#pragma unroll
        for (int i = 0; i < 4; i++) acc[i] = make_float2(0.f, 0.f);
    }
    int j = off[node] + q;
    int jend = off[node + 1];
    if (j + 4 < jend) {
        int s0 = rec[j], s1 = rec[j + 4];
        for (; j + 12 < jend; j += 8) {
            int n0 = rec[j + 8], n1 = rec[j + 12];      // prefetch next pair
            uint4 v0 = ((const uint4*)(A + (size_t)s0 * DHID))[ql];
            uint4 v1 = ((const uint4*)(A + (size_t)s1 * DHID))[ql];
            float w0 = dinv[s0] * di;
            float w1 = dinv[s1] * di;
            acc[0].x += bf_lo(v0.x) * w0 + bf_lo(v1.x) * w1;
            acc[0].y += bf_hi(v0.x) * w0 + bf_hi(v1.x) * w1;
            acc[1].x += bf_lo(v0.y) * w0 + bf_lo(v1.y) * w1;
            acc[1].y += bf_hi(v0.y) * w0 + bf_hi(v1.y) * w1;
            acc[2].x += bf_lo(v0.z) * w0 + bf_lo(v1.z) * w1;
            acc[2].y += bf_hi(v0.z) * w0 + bf_hi(v1.z) * w1;
            acc[3].x += bf_lo(v0.w) * w0 + bf_lo(v1.w) * w1;
            acc[3].y += bf_hi(v0.w) * w0 + bf_hi(v1.w) * w1;
            s0 = n0; s1 = n1;
        }
        {
            uint4 v0 = ((const uint4*)(A + (size_t)s0 * DHID))[ql];
            uint4 v1 = ((const uint4*)(A + (size_t)s1 * DHID))[ql];
            float w0 = dinv[s0] * di;
            float w1 = dinv[s1] * di;
            acc[0].x += bf_lo(v0.x) * w0 + bf_lo(v1.x) * w1;
            acc[0].y += bf_hi(v0.x) * w0 + bf_hi(v1.x) * w1;
            acc[1].x += bf_lo(v0.y) * w0 + bf_lo(v1.y) * w1;
            acc[1].y += bf_hi(v0.y) * w0 + bf_hi(v1.y) * w1;
            acc[2].x += bf_lo(v0.z) * w0 + bf_lo(v1.z) * w1;
            acc[2].y += bf_hi(v0.z) * w0 + bf_hi(v1.z) * w1;
            acc[3].x += bf_lo(v0.w) * w0 + bf_lo(v1.w) * w1;
            acc[3].y += bf_hi(v0.w) * w0 + bf_hi(v1.w) * w1;
            j += 8;
        }
    }
    if (j < jend) {
        int s0 = rec[j];
        uint4 v0 = ((const uint4*)(A + (size_t)s0 * DHID))[ql];
        float w0 = dinv[s0] * di;
        acc[0].x += bf_lo(v0.x) * w0;
        acc[0].y += bf_hi(v0.x) * w0;
        acc[1].x += bf_lo(v0.y) * w0;
        acc[1].y += bf_hi(v0.y) * w0;
        acc[2].x += bf_lo(v0.z) * w0;
        acc[2].y += bf_hi(v0.z) * w0;
        acc[3].x += bf_lo(v0.w) * w0;
        acc[3].y += bf_hi(v0.w) * w0;
    }
#pragma unroll
    for (int i = 0; i < 4; i++) {
        acc[i].x += __shfl_xor(acc[i].x, 16);
        acc[i].y += __shfl_xor(acc[i].y, 16);
        acc[i].x += __shfl_xor(acc[i].x, 32);
        acc[i].y += __shfl_xor(acc[i].y, 32);
    }
    if (q == 0) {
        if (mode == 1) {
#pragma unroll
            for (int i = 0; i < 4; i++) {
                acc[i].x = fmaxf(acc[i].x, 0.f);
                acc[i].y = fmaxf(acc[i].y, 0.f);
            }
        }
        uint4 pk;
        pk.x = pack_bf16x2(acc[0].x, acc[0].y);
        pk.y = pack_bf16x2(acc[1].x, acc[1].y);
        pk.z = pack_bf16x2(acc[2].x, acc[2].y);
        pk.w = pack_bf16x2(acc[3].x, acc[3].y);
        ((uint4*)(Bout + (size_t)node * DHID))[ql] = pk;
    }
}

// ---------------- fused tail: mean-pool(B2b) -> @W2+b2 -> GRU gates -> LN -> head ----------------
// One block per graph. B2b holds Â·H1 (bf16); layer-2's W2/b2 are commuted here:
// g2 = mean(rows) @ W2 + b2 — a 128-dot per output vs the deleted 100k-row gemm.
__global__ __launch_bounds__(256) void tail_head(const unsigned short* __restrict__ B,
                                                 const int* __restrict__ batch,
                                                 const unsigned short* __restrict__ Wt2,
                                                 const float* __restrict__ b2,
                                                 const unsigned short* __restrict__ Wihb,
                                                 const float* __restrict__ b_ih,
                                                 const float* __restrict__ b_hh,
                                                 const float* __restrict__ W_lin,
                                                 const float* __restrict__ b_lin,
                                                 float* __restrict__ out,
                                                 int N, int G) {
    __shared__ float grow[128];
    __shared__ float psum[4][128];
    __shared__ float g2[128];
    __shared__ float gi[384];
    __shared__ float red[4];
    __shared__ int se[2];
    const int t = threadIdx.x;
    const int g = blockIdx.x;
    if (t < 2) {
        int target = g + t, lo = 0, hi = N;
        while (lo < hi) {
            int mid = (lo + hi) >> 1;
            if (batch[mid] < target) lo = mid + 1; else hi = mid;
        }
        se[t] = lo;
    }
    __syncthreads();
    const int s = se[0], e = se[1];

    // mean over the graph's rows: 4 rows/iter, one uint (2 channels) per lane
    const int c2 = t & 63;
    const int rh = t >> 6;
    float sx = 0.f, sy = 0.f;
    for (int r = s + rh; r < e; r += 4) {
        unsigned u = *(const unsigned*)(B + (size_t)r * DHID + c2 * 2);
        sx += bf_lo(u);
        sy += bf_hi(u);
    }
    *(float2*)&psum[rh][c2 * 2] = make_float2(sx, sy);
    __syncthreads();
    if (t < 128) {
        grow[t] = (psum[0][t] + psum[1][t] + psum[2][t] + psum[3][t]) /
                  fmaxf((float)(e - s), 1.0f);
    }
    __syncthreads();

    // g2[n] = dot(grow, W2[:,n]) + b2[n]   (Wt2 row n = column n of W2, bf16)
    if (t < 128) {
        float a = 0.f;
        const uint4* wr = (const uint4*)(Wt2 + (size_t)t * DHID);
#pragma unroll
        for (int k8 = 0; k8 < 16; k8++) {
            uint4 wv = wr[k8];
            const float* gk = &grow[k8 * 8];
            a += bf_lo(wv.x) * gk[0] + bf_hi(wv.x) * gk[1]
               + bf_lo(wv.y) * gk[2] + bf_hi(wv.y) * gk[3]
               + bf_lo(wv.z) * gk[4] + bf_hi(wv.z) * gk[5]
               + bf_lo(wv.w) * gk[6] + bf_hi(wv.w) * gk[7];
        }
        g2[t] = a + b2[t];
    }
    __syncthreads();

    // gi[o] = dot(g2, Wih[o,:]); thread t handles o=t, and o=256+t for t<128
    {
        float a0 = 0.f;
        const uint4* wr = (const uint4*)(Wihb + (size_t)t * DHID);
#pragma unroll
        for (int k8 = 0; k8 < 16; k8++) {
            uint4 wv = wr[k8];
            const float* gk = &g2[k8 * 8];
            a0 += bf_lo(wv.x) * gk[0] + bf_hi(wv.x) * gk[1]
                + bf_lo(wv.y) * gk[2] + bf_hi(wv.y) * gk[3]
                + bf_lo(wv.z) * gk[4] + bf_hi(wv.z) * gk[5]
                + bf_lo(wv.w) * gk[6] + bf_hi(wv.w) * gk[7];
        }
        gi[t] = a0;
    }
    if (t < 128) {
        float a1 = 0.f;
        const uint4* wr = (const uint4*)(Wihb + (size_t)(256 + t) * DHID);
#pragma unroll
        for (int k8 = 0; k8 < 16; k8++) {
            uint4 wv = wr[k8];
            const float* gk = &g2[k8 * 8];
            a1 += bf_lo(wv.x) * gk[0] + bf_hi(wv.x) * gk[1]
                + bf_lo(wv.y) * gk[2] + bf_hi(wv.y) * gk[3]
                + bf_lo(wv.z) * gk[4] + bf_hi(wv.z) * gk[5]
                + bf_lo(wv.w) * gk[6] + bf_hi(wv.w) * gk[7];
        }
        gi[256 + t] = a1;
    }
    __syncthreads();

    float y = 0.f, wl = 0.f;
    if (t < 128) {
        float d0 = gi[t], d1 = gi[128 + t], d2 = gi[256 + t];
        float rg = 1.f / (1.f + expf(-(d0 + b_ih[t] + b_hh[t])));
        float zg = 1.f / (1.f + expf(-(d1 + b_ih[128 + t] + b_hh[128 + t])));
        float ng = tanhf(d2 + b_ih[256 + t] + rg * b_hh[256 + t]);
        y = fmaxf((1.f - zg) * ng, 0.f);
        wl = W_lin[t];
    }
    auto blockSum = [&](float v) -> float {
#pragma unroll
        for (int o = 1; o < 64; o <<= 1) v += __shfl_xor(v, o);
        __syncthreads();
        if ((t & 63) == 0) red[t >> 6] = v;
        __syncthreads();
        return red[0] + red[1] + red[2] + red[3];
    };
    float mu = blockSum(y) * (1.f / 128.f);
    float dy = (t < 128) ? (y - mu) : 0.f;
    float var = blockSum(dy * dy) * (1.f / 128.f);
    float yn = dy * rsqrtf(var + 1e-5f);
    float tot = blockSum(yn * wl);
    if (t == 0) out[g] = tot + b_lin[0];
}

extern "C" void kernel_launch(void* const* d_in, const int* in_sizes, int n_in,
                              void* d_out, int out_size, void* d_ws, size_t ws_size,
                              hipStream_t stream) {
    const float* x     = (const float*)d_in[0];
    const int*   ei    = (const int*)d_in[1];
    const int*   batch = (const int*)d_in[2];
    const float* W1    = (const float*)d_in[3];
    const float* b1    = (const float*)d_in[4];
    const float* W2    = (const float*)d_in[5];
    const float* b2    = (const float*)d_in[6];
    const float* W_ih  = (const float*)d_in[7];
    // d_in[8] = W_hh unused (h0 == 0)
    const float* b_ih  = (const float*)d_in[9];
    const float* b_hh  = (const float*)d_in[10];
    const float* W_lin = (const float*)d_in[11];
    const float* b_lin = (const float*)d_in[12];
    float* out = (float*)d_out;

    const int N = in_sizes[0] / DHID;
    const int E = in_sizes[1] / 2;
    const int G = out_size;
    const int* src = ei;
    const int* dst = ei + E;
    const int NB = (N + (1 << SH) - 1) >> SH;   // buckets (<= 1024)

    auto align256 = [](size_t v) { return (v + 255) & ~(size_t)255; };
    char* p = (char*)d_ws;
    size_t used = 0;
    auto carve = [&](size_t bytes) -> char* {
        char* q = p + used;
        used += align256(bytes);
        return q;
    };

    int*   off    = (int*)carve(((size_t)N + 1) * 4);
    int*   bcur   = (int*)carve(1024 * 4);                 // contiguous with zbias:
    float* zbias  = (float*)carve(128 * 4);                // one memset covers both
    float* dinv   = (float*)carve((size_t)N * 4);
    unsigned* staged = (unsigned*)carve(((size_t)NB << CAPSH) * 4);
    int*   rec    = (int*)carve((size_t)E * 4);
    unsigned short* Wt1  = (unsigned short*)carve((size_t)128 * 128 * 2);
    unsigned short* Wt2  = (unsigned short*)carve((size_t)128 * 128 * 2);
    unsigned short* Wihb = (unsigned short*)carve((size_t)3 * 128 * 128 * 2);
    unsigned short* A    = (unsigned short*)carve((size_t)N * DHID * 2);   // bf16: x@W1
    unsigned short* B1b  = (unsigned short*)carve((size_t)N * DHID * 2);   // bf16: H1 (relu'd)
    size_t matB = (size_t)N * DHID * 2;
    unsigned short* B2b;
    if (ws_size >= used + matB) {
        B2b = (unsigned short*)carve(matB);
    } else {
        B2b = (unsigned short*)d_in[0];   // x fully consumed by gemm-1 before agg-2 writes
    }

    dim3 blk(256);
    int nb_g  = (N + 63) / 64;
    int nb_ag = (N + 3) / 4;
    int nb_bin = (E + BIN_T - 1) / BIN_T;
    int nb_wp  = (81920 + 255) / 256;

    // ---- CSR build (weight prep folded into bin_edges, gemm1 folded into scatter) ----
    hipMemsetAsync(bcur, 0, 1024 * 4 + 256 + 128 * 4, stream);   // bcur + pad + zbias
    bin_edges<<<nb_bin + nb_wp, blk, 0, stream>>>(src, dst, bcur, staged,
                                                  W1, W2, W_ih, Wt1, Wt2, Wihb,
                                                  E, NB, nb_bin);
    scatter_gemm<<<NB + nb_g, blk, 0, stream>>>(staged, bcur, off, dinv, rec,
                                                N, E, NB, x, Wt1, A);

    // ---- layer 1: B1b = ReLU(Â·A + b1) ----
    aggregate<<<nb_ag, blk, 0, stream>>>(A, dinv, off, rec, b1, B1b, N, 1);

    // ---- layer 2 aggregation (W2, b2 commuted into tail): B2b = Â·B1b ----
    aggregate<<<nb_ag, blk, 0, stream>>>(B1b, dinv, off, rec, zbias, B2b, N, 0);

    // ---- tail: pool -> @W2+b2 -> GRU -> LN -> head ----
    tail_head<<<G, blk, 0, stream>>>(B2b, batch, Wt2, b2, Wihb, b_ih, b_hh,
                                     W_lin, b_lin, out, N, G);
}